// Round 4
// baseline (441.310 us; speedup 1.0000x reference)
//
#include <hip/hip_runtime.h>
#include <hip/hip_bf16.h>
#include <cstdint>
#include <cstddef>

typedef unsigned short u16;
typedef __attribute__((ext_vector_type(8))) short short8;   // 8 bf16 = 4 VGPRs (MFMA A/B frag)
typedef __attribute__((ext_vector_type(4))) float f32x4;    // MFMA C/D frag (16x16)
typedef __attribute__((ext_vector_type(16))) float f32x16;  // MFMA C/D frag (32x32)

__device__ __forceinline__ u16 f2bf(float f) {
    union { float f; uint32_t u; } v; v.f = f;
    uint32_t u = v.u;
    return (u16)((u + 0x7fffu + ((u >> 16) & 1u)) >> 16);   // RNE
}
__device__ __forceinline__ float bf2f(u16 u) {
    union { uint32_t u; float f; } v; v.u = ((uint32_t)u) << 16;
    return v.f;
}
// pack two f32 -> one dword of 2 bf16 (lo|hi<<16), pure bit-ops
__device__ __forceinline__ uint32_t pk2(float lo, float hi) {
    return (uint32_t)f2bf(lo) | ((uint32_t)f2bf(hi) << 16);
}

// async global->LDS 16B copy (m97: global_load_lds_dwordx4).
__device__ __forceinline__ void async_cp16(const u16* g, u16* l) {
    __builtin_amdgcn_global_load_lds(
        (const __attribute__((address_space(1))) unsigned int*)g,
        (__attribute__((address_space(3))) unsigned int*)l, 16, 0, 0);
}

// ---------------- cast fp32 -> bf16 (vectorized) ----------------
__global__ __launch_bounds__(256) void cast_f32_bf16(const float* __restrict__ in,
                                                     u16* __restrict__ out, int n) {
    int i = (blockIdx.x * 256 + threadIdx.x) * 4;
    if (i >= n) return;
    float4 v = *(const float4*)(in + i);
    ushort4 r;
    r.x = f2bf(v.x); r.y = f2bf(v.y); r.z = f2bf(v.z); r.w = f2bf(v.w);
    *(ushort4*)(out + i) = r;
}

// ---------------- W (K,N) fp32 -> Wt (N,K) bf16 (optionally pre-scaled) ----------------
__global__ __launch_bounds__(256) void transpose_cast(const float* __restrict__ W,
                                                      u16* __restrict__ Wt, int K, int N,
                                                      float smul) {
    __shared__ u16 tile[64][72];
    int kt = blockIdx.x * 64, nt = blockIdx.y * 64;
    int t = threadIdx.x;
#pragma unroll
    for (int i = 0; i < 16; i++) {
        int idx = t + i * 256; int kl = idx >> 6, nl = idx & 63;
        tile[kl][nl] = f2bf(W[(size_t)(kt + kl) * N + nt + nl] * smul);
    }
    __syncthreads();
#pragma unroll
    for (int i = 0; i < 16; i++) {
        int idx = t + i * 256; int nl = idx >> 6, kl = idx & 63;
        Wt[(size_t)(nt + nl) * K + kt + kl] = tile[kl][nl];
    }
}

// ---------------- bf16 GEMM (m97 structure), compile-time shapes ----------------
template <int OUTF32, int KDIM, int NDIM>
__global__ __launch_bounds__(256) void gemm_bt(const u16* __restrict__ A, int lda,
                                               const u16* __restrict__ Bt,
                                               void* __restrict__ Cout, int ldc) {
    __shared__ __align__(16) u16 Al[128 * 32];
    __shared__ __align__(16) u16 Bl[128 * 32];
    int m0 = blockIdx.x * 128, n0 = blockIdx.y * 128;
    int t = threadIdx.x;
    int w = t >> 6, l = t & 63;
    int lm = l & 15, lq = l >> 4;
    int wm = (w >> 1) * 64, wn = (w & 1) * 64;
    f32x4 acc[4][4] = {};

    for (int k0 = 0; k0 < KDIM; k0 += 32) {
#pragma unroll
        for (int c = 0; c < 2; c++) {
            int chunk = w * 128 + c * 64 + l;
            int row = chunk >> 2, col8 = (chunk & 3) * 8;
            async_cp16(A + (size_t)(m0 + row) * lda + k0 + col8,
                       Al + (w * 128 + c * 64) * 8);
            int brow = n0 + row;
            if (NDIM % 128 != 0) { if (brow >= NDIM) brow = NDIM - 1; }
            async_cp16(Bt + (size_t)brow * KDIM + k0 + col8,
                       Bl + (w * 128 + c * 64) * 8);
        }
        __syncthreads();
        short8 af[4], bfr[4];
#pragma unroll
        for (int mt = 0; mt < 4; mt++)
            af[mt] = *(const short8*)(Al + (wm + mt * 16 + lm) * 32 + lq * 8);
#pragma unroll
        for (int nt = 0; nt < 4; nt++)
            bfr[nt] = *(const short8*)(Bl + (wn + nt * 16 + lm) * 32 + lq * 8);
#pragma unroll
        for (int mt = 0; mt < 4; mt++)
#pragma unroll
            for (int nt = 0; nt < 4; nt++)
                acc[mt][nt] = __builtin_amdgcn_mfma_f32_16x16x32_bf16(af[mt], bfr[nt], acc[mt][nt], 0, 0, 0);
        __syncthreads();
    }
#pragma unroll
    for (int mt = 0; mt < 4; mt++) {
#pragma unroll
        for (int nt = 0; nt < 4; nt++) {
            int col = n0 + wn + nt * 16 + lm;
            if (col < NDIM) {
#pragma unroll
                for (int r = 0; r < 4; r++) {
                    int row = m0 + wm + mt * 16 + lq * 4 + r;
                    if (OUTF32) ((float*)Cout)[(size_t)row * ldc + col] = acc[mt][nt][r];
                    else        ((u16*)Cout)[(size_t)row * ldc + col] = f2bf(acc[mt][nt][r]);
                }
            }
        }
    }
}

// ---------------- RoPE in-place on (rows, nheads*64) bf16, row stride `stride` ----------------
__global__ __launch_bounds__(256) void rope_kernel(u16* __restrict__ x, int rows,
                                                   int nheads, int Smask, int stride) {
    int i = blockIdx.x * 256 + threadIdx.x;
    int total = rows * nheads * 32;
    if (i >= total) return;
    int j = i & 31;
    int h = (i >> 5) % nheads;
    int row = i / (32 * nheads);
    int pos = row & Smask;
    float f = exp2f((float)j * -0.4152410118609828f);
    float ang = (float)pos * f;
    float c = cosf(ang), s = sinf(ang);
    u16* p = x + (size_t)row * stride + h * 64 + j;
    float x1 = bf2f(p[0]), x2 = bf2f(p[32]);
    p[0]  = f2bf(x1 * c - x2 * s);
    p[32] = f2bf(x2 * c + x1 * s);
}

// ---------------- V slice of kv -> v_t (B,H,128,S) bf16 ----------------
__global__ __launch_bounds__(256) void transpose_v(const u16* __restrict__ kv,
                                                   u16* __restrict__ vt, int S) {
    __shared__ u16 tile[64][72];
    int bh = blockIdx.z; int b = bh >> 4, h = bh & 15;
    int s0 = blockIdx.x * 64, d0 = blockIdx.y * 64;
    int t = threadIdx.x;
#pragma unroll
    for (int i = 0; i < 16; i++) {
        int idx = t + i * 256; int sl = idx >> 6, dl = idx & 63;
        tile[sl][dl] = kv[(size_t)(b * S + s0 + sl) * 4096 + 2048 + h * 128 + d0 + dl];
    }
    __syncthreads();
#pragma unroll
    for (int i = 0; i < 16; i++) {
        int idx = t + i * 256; int dl = idx >> 6, sl = idx & 63;
        vt[((size_t)(bh * 128 + d0 + dl)) * S + s0 + sl] = tile[sl][dl];
    }
}

// ---------------- Flash MLA attention v8: uniform blocks + dbuf single-barrier ----------------
// Round-3 post-mortem: v7's grid pairing ran the pair in PARALLEL -> short block exits
// early -> long block runs alone (occupancy 12.6% vs 25% max, ~half wave-seconds lost).
// v8 (compute/softmax/P-path byte-identical to v7):
//  * sequential two-half pairing (v4-proven): block y runs q-tile y then 15-y ->
//    exactly 34 k-tile iterations per block, zero tail. grid (32,8)=256 blocks, 1/CU,
//    XCD pinning preserved (id%8 = bh%8).
//  * K/V LDS double-buffered (88 KB, fits the 1-block/CU the grid dictates):
//    ONE barrier per tile; staging ds_writes overlap current tile's compute.
//    Guarded compute (no `continue`) so all waves reach the barrier.
__global__ __launch_bounds__(256, 1) void mla_attn(const u16* __restrict__ qc, int qcs,
                                                   const u16* __restrict__ qr, int qrs,
                                                   const u16* __restrict__ kvbuf,
                                                   const u16* __restrict__ kr, int krs,
                                                   const u16* __restrict__ vt,
                                                   u16* __restrict__ out, int S) {
    __shared__ __align__(16) u16 Kl[2][64 * 200];    // 2 x 25.6 KB
    __shared__ __align__(16) u16 Vl[2][128 * 72];    // 2 x 18.4 KB
    const float NEG = -1e30f;
    int bh = blockIdx.x; int b = bh >> 4, h = bh & 15;   // XCD-pinning: XCD = bh%8
    int y = blockIdx.y;                              // 0..7
    int t = threadIdx.x, w = t >> 6, l = t & 63;
    int ln = l & 31, hi = l >> 5;

    short8 kreg[6], vreg[4];
    auto load_tile = [&](int kbase) {
#pragma unroll
        for (int c = 0; c < 6; c++) {                 // K: 64 rows x 24 chunks(16B)
            int idx = t + c * 256;
            int row = idx / 24, col = (idx % 24) * 8;
            const u16* src = (col < 128)
                ? kvbuf + (size_t)(b * S + kbase + row) * 4096 + h * 128 + col
                : kr + (size_t)(b * S + kbase + row) * krs + (col - 128);
            kreg[c] = *(const short8*)src;
        }
#pragma unroll
        for (int c = 0; c < 4; c++) {                 // V^T: 128 rows x 8 chunks(16B)
            int idx = t + c * 256;
            int row = idx >> 3, col = (idx & 7) * 8;
            vreg[c] = *(const short8*)(vt + ((size_t)bh * 128 + row) * S + kbase + col);
        }
    };
    auto store_tile = [&](int bufi) {
#pragma unroll
        for (int c = 0; c < 6; c++) {
            int idx = t + c * 256;
            int row = idx / 24, col = (idx % 24) * 8;
            *(short8*)(Kl[bufi] + row * 200 + col) = kreg[c];
        }
#pragma unroll
        for (int c = 0; c < 4; c++) {
            int idx = t + c * 256;
            int row = idx >> 3, col = (idx & 7) * 8;
            *(short8*)(Vl[bufi] + row * 72 + col) = vreg[c];
        }
    };

    for (int half = 0; half < 2; half++) {
        int qt = half ? (15 - y) : y;                 // sequential pair: 34 tiles total
        int qrow = qt * 128 + w * 32;                 // this wave's 32 q-rows
        int ntiles = 2 * qt + 2;

        // Q B-frags for 32x32x16: lane holds col q=ln, k = ks*16 + hi*8 + j (pre-scaled)
        short8 bq[12];
        {
            const u16* qc_row = qc + (size_t)(b * S + qrow + ln) * qcs + h * 128;
#pragma unroll
            for (int ks = 0; ks < 8; ks++) bq[ks] = *(const short8*)(qc_row + ks * 16 + hi * 8);
            const u16* qr_row = qr + (size_t)(b * S + qrow + ln) * qrs + h * 64;
#pragma unroll
            for (int ks = 0; ks < 4; ks++) bq[8 + ks] = *(const short8*)(qr_row + ks * 16 + hi * 8);
        }

        f32x16 o[4] = {};                             // O^T: 4 dim-tiles x (32x32 C)
        float m_s = 0.0f, l_s = 0.f;                  // running max (ref 0) / denom

        // prologue: stage tile 0 into buf 0 (prior half's reads sealed by its last barrier)
        load_tile(0);
        store_tile(0);
        __syncthreads();

        for (int kt = 0; kt < ntiles; kt++) {
            int kbase = kt * 64;
            int cur = kt & 1;
            if (kt + 1 < ntiles) load_tile(kbase + 64);   // global->regs, hidden by compute

            if (kbase <= qrow + 31) {                 // guarded compute (all waves barrier)
                const u16* Kb = Kl[cur];
                const u16* Vb = Vl[cur];

                // S^T: sacc[kt2][r] = S_log2[key=kbase+kt2*32+(r&3)+8(r>>2)+4hi][q=qrow+ln]
                f32x16 sacc[2] = {};
                __builtin_amdgcn_s_setprio(1);
#pragma unroll
                for (int ks = 0; ks < 12; ks++) {
                    short8 ak0 = *(const short8*)(Kb + ln * 200 + ks * 16 + hi * 8);
                    short8 ak1 = *(const short8*)(Kb + (32 + ln) * 200 + ks * 16 + hi * 8);
                    sacc[0] = __builtin_amdgcn_mfma_f32_32x32x16_bf16(ak0, bq[ks], sacc[0], 0, 0, 0);
                    sacc[1] = __builtin_amdgcn_mfma_f32_32x32x16_bf16(ak1, bq[ks], sacc[1], 0, 0, 0);
                }
                __builtin_amdgcn_s_setprio(0);

                if (kbase + 63 > qrow) {              // diagonal tiles: causal mask (finite)
                    int qi = qrow + ln;
#pragma unroll
                    for (int kt2 = 0; kt2 < 2; kt2++)
#pragma unroll
                        for (int r = 0; r < 16; r++) {
                            int key = kbase + kt2 * 32 + (r & 3) + 8 * (r >> 2) + 4 * hi;
                            if (key > qi) sacc[kt2][r] = NEG;
                        }
                }

                // online softmax (log2 domain, ref max 0), lane pair (l, l^32) shares q-row
                float mx = NEG;
#pragma unroll
                for (int kt2 = 0; kt2 < 2; kt2++)
#pragma unroll
                    for (int r = 0; r < 16; r++) mx = fmaxf(mx, sacc[kt2][r]);
                mx = fmaxf(mx, __shfl_xor(mx, 32));
                if (!__all(mx - m_s <= 8.0f)) {       // defer-max (T13): P <= 2^8 otherwise
                    float mnew = fmaxf(m_s, mx);
                    float alpha = exp2f(m_s - mnew);
                    m_s = mnew;
                    l_s *= alpha;
#pragma unroll
                    for (int dt = 0; dt < 4; dt++) o[dt] *= alpha;
                }

                // P = 2^(S-m): exp + pack to bf16 B-frags in-register; cross-half via shfl_xor
                float rs = 0.f;
                short8 bp[2][2];
#pragma unroll
                for (int kt2 = 0; kt2 < 2; kt2++) {
                    float p[16];
#pragma unroll
                    for (int r = 0; r < 16; r++) p[r] = exp2f(sacc[kt2][r] - m_s);
#pragma unroll
                    for (int r = 0; r < 16; r++) rs += p[r];
                    uint32_t c0 = pk2(p[0], p[1]),  c1 = pk2(p[2], p[3]);
                    uint32_t c2 = pk2(p[4], p[5]),  c3 = pk2(p[6], p[7]);
                    uint32_t e0 = __shfl_xor(c0, 32), e1 = __shfl_xor(c1, 32);
                    uint32_t e2 = __shfl_xor(c2, 32), e3 = __shfl_xor(c3, 32);
                    union { uint32_t u[4]; short8 s; } f0;
                    f0.u[0] = hi ? e2 : c0;
                    f0.u[1] = hi ? e3 : c1;
                    f0.u[2] = hi ? c2 : e0;
                    f0.u[3] = hi ? c3 : e1;
                    bp[kt2][0] = f0.s;
                    uint32_t c4 = pk2(p[8], p[9]),   c5 = pk2(p[10], p[11]);
                    uint32_t c6 = pk2(p[12], p[13]), c7 = pk2(p[14], p[15]);
                    uint32_t e4 = __shfl_xor(c4, 32), e5 = __shfl_xor(c5, 32);
                    uint32_t e6 = __shfl_xor(c6, 32), e7 = __shfl_xor(c7, 32);
                    union { uint32_t u[4]; short8 s; } f1;
                    f1.u[0] = hi ? e6 : c4;
                    f1.u[1] = hi ? e7 : c5;
                    f1.u[2] = hi ? c6 : e4;
                    f1.u[3] = hi ? c7 : e5;
                    bp[kt2][1] = f1.s;
                }
                rs += __shfl_xor(rs, 32);
                l_s += rs;

                // O^T += V^T · P : A=V^T[dim][key] from LDS, B=P[key][q] in regs
                __builtin_amdgcn_s_setprio(1);
#pragma unroll
                for (int kt2 = 0; kt2 < 2; kt2++)
#pragma unroll
                    for (int s = 0; s < 2; s++)
#pragma unroll
                        for (int dt = 0; dt < 4; dt++) {
                            short8 av = *(const short8*)(Vb + (dt * 32 + ln) * 72 + kt2 * 32 + s * 16 + hi * 8);
                            o[dt] = __builtin_amdgcn_mfma_f32_32x32x16_bf16(av, bp[kt2][s], o[dt], 0, 0, 0);
                        }
                __builtin_amdgcn_s_setprio(0);
            }

            if (kt + 1 < ntiles) store_tile(cur ^ 1); // write OTHER buffer (no read conflict)
            __syncthreads();                          // writes visible; reads of cur sealed
        }

        // epilogue: C col=q=ln, row=dim=dt*32+(r&3)+8*(r>>2)+4hi -> 4-consecutive-dim packs
        float inv = 1.0f / l_s;
        u16* orow = out + (size_t)(b * S + qrow + ln) * 2048 + h * 128;
#pragma unroll
        for (int dt = 0; dt < 4; dt++)
#pragma unroll
            for (int g = 0; g < 4; g++) {
                ushort4 pk4;
                pk4.x = f2bf(o[dt][g * 4 + 0] * inv);
                pk4.y = f2bf(o[dt][g * 4 + 1] * inv);
                pk4.z = f2bf(o[dt][g * 4 + 2] * inv);
                pk4.w = f2bf(o[dt][g * 4 + 3] * inv);
                *(ushort4*)(orow + dt * 32 + g * 8 + hi * 4) = pk4;
            }
    }
}

extern "C" void kernel_launch(void* const* d_in, const int* in_sizes, int n_in,
                              void* d_out, int out_size, void* d_ws, size_t ws_size,
                              hipStream_t stream) {
    const int B = 2, S = 2048, D = 2048, H = 16;
    const int M = B * S;                       // 4096
    const int NP = 3648;                       // merged proj cols: 2048+1024+512+64
    const int NPpad = 3712;                    // 29 tiles of 128
    // 1/sqrt(192) * log2(e): softmax runs in exp2 domain (folded into Wq/Wq_rope)
    const float scale = 0.07216878364870323f * 1.4426950408889634f;
    const float* x    = (const float*)d_in[0];
    const float* Wq   = (const float*)d_in[1];
    const float* Wqr  = (const float*)d_in[2];
    const float* Wkvd = (const float*)d_in[3];
    const float* Wkvu = (const float*)d_in[4];
    const float* Wkr  = (const float*)d_in[5];
    const float* Wo   = (const float*)d_in[6];

    u16* p = (u16*)d_ws;
    u16* xb     = p; p += (size_t)M * D;             // 16.8 MB
    u16* WprojT = p; p += (size_t)NPpad * 2048;      // rows: [Wq|Wqr|Wkvd|Wkr|pad]
    u16* WkvuT  = p; p += (size_t)4096 * 512;
    u16* WoT    = p; p += (size_t)2048 * 2048;
    u16* proj   = p; p += (size_t)M * NPpad;         // [q_c|q_r|c_kv|k_r] row-major
    u16* kv     = p; p += (size_t)M * 4096;
    u16* v_t    = p; p += (size_t)B * H * 128 * S;
    u16* attn   = p; p += (size_t)M * 2048;

    u16* q_c = proj;                 // cols 0..2047
    u16* q_r = proj + 2048;          // cols 2048..3071
    u16* ckv = proj + 3072;          // cols 3072..3583
    u16* k_r = proj + 3584;          // cols 3584..3647

    // 1) casts / transposes (Wq, Wq_rope pre-scaled by 1/sqrt(192)*log2e)
    cast_f32_bf16<<<(M * D) / 4 / 256, 256, 0, stream>>>(x, xb, M * D);
    transpose_cast<<<dim3(32, 32), 256, 0, stream>>>(Wq,   WprojT,               2048, 2048, scale);
    transpose_cast<<<dim3(32, 16), 256, 0, stream>>>(Wqr,  WprojT + 2048 * 2048, 2048, 1024, scale);
    transpose_cast<<<dim3(32, 8),  256, 0, stream>>>(Wkvd, WprojT + 3072 * 2048, 2048, 512, 1.0f);
    transpose_cast<<<dim3(32, 1),  256, 0, stream>>>(Wkr,  WprojT + 3584 * 2048, 2048, 64, 1.0f);
    transpose_cast<<<dim3(8, 64),  256, 0, stream>>>(Wkvu, WkvuT, 512, 4096, 1.0f);
    transpose_cast<<<dim3(32, 32), 256, 0, stream>>>(Wo,   WoT,   2048, 2048, 1.0f);

    // 2) merged projection GEMM: proj = xb @ WprojT^T  (grid 32x29 = 928 blocks)
    gemm_bt<0, 2048, NP><<<dim3(32, 29), 256, 0, stream>>>(xb, 2048, WprojT, proj, NPpad);

    // 3) RoPE (in place on proj slices; q_r pre-scaled — rotation linear, scale commutes)
    rope_kernel<<<(M * 16 * 32) / 256, 256, 0, stream>>>(q_r, M, 16, S - 1, NPpad);
    rope_kernel<<<(M * 32) / 256, 256, 0, stream>>>(k_r, M, 1, S - 1, NPpad);

    // 4) kv up-projection (A = c_kv inside proj, lda = NPpad), V transpose
    gemm_bt<0, 512, 4096><<<dim3(32, 32), 256, 0, stream>>>(ckv, NPpad, WkvuT, kv, 4096);
    transpose_v<<<dim3(32, 2, 32), 256, 0, stream>>>(kv, v_t, S);

    // 5) attention — grid (bh, 8): uniform 34-tile blocks (sequential pair y, 15-y)
    mla_attn<<<dim3(32, 8), 256, 0, stream>>>(q_c, NPpad, q_r, NPpad, kv, k_r, NPpad,
                                              v_t, attn, S);

    // 6) output projection -> fp32 d_out
    gemm_bt<1, 2048, 2048><<<dim3(32, 16), 256, 0, stream>>>(attn, 2048, WoT, d_out, 2048);
}